// Round 1
// baseline (225.275 us; speedup 1.0000x reference)
//
#include <hip/hip_runtime.h>

#define H_ 448
#define W_ 96
#define CIN_ 128
#define HW_ (H_*W_)   // 43008

__device__ __forceinline__ float lrelu(float v){ return v > 0.0f ? v : 0.01f*v; }

__global__ __launch_bounds__(384, 3)
void cls3_fused(const float* __restrict__ X,
                const float* __restrict__ w1_0, const float* __restrict__ b1_0,
                const float* __restrict__ w1_1, const float* __restrict__ b1_1,
                const float* __restrict__ w1_2, const float* __restrict__ b1_2,
                const float* __restrict__ w2_0, const float* __restrict__ b2_0,
                const float* __restrict__ w2_1, const float* __restrict__ b2_1,
                const float* __restrict__ w2_2, const float* __restrict__ b2_2,
                const float* __restrict__ w3_0, const float* __restrict__ b3_0,
                const float* __restrict__ w3_1, const float* __restrict__ b3_1,
                const float* __restrict__ w3_2, const float* __restrict__ b3_2,
                int* __restrict__ out)
{
    __shared__ float s_w0[4096];     // w1_0[h] as [o=32][i=128]
    __shared__ float s_w1[1024];     // w1_1[h] as [o=32][i=32]
    __shared__ float s_w2[256];      // w1_2[h] as [o=8][i=32]
    __shared__ float s_A[W_*33];     // activation ping (stride 33: conflict-free)
    __shared__ float s_B[W_*33];     // activation pong
    __shared__ int   s_ind[W_];      // per-pixel routing index

    const int h  = blockIdx.x;
    const int t  = threadIdx.x;
    const int w  = t % W_;           // pixel within line
    const int s  = t / W_;           // 0..3: owns output channels [s*8, s*8+8)
    const int hw = h*W_ + w;

    // ---- stage-1 weight staging (coalesced global, linear LDS writes) ----
    {
        const float* g0 = w1_0 + (size_t)h*4096;
        for (int j = t; j < 4096; j += 384) s_w0[j] = g0[j];
        const float* g1 = w1_1 + (size_t)h*1024;
        for (int j = t; j < 1024; j += 384) s_w1[j] = g1[j];
        const float* g2 = w1_2 + (size_t)h*256;
        for (int j = t; j < 256; j += 384) s_w2[j] = g2[j];
    }
    __syncthreads();

    // ================= stage 1 =================
    // L0: 128 -> 32   (x from global, w from LDS, float4 along i)
    {
        float acc[8];
        const float* bp = b1_0 + h*32 + s*8;
        #pragma unroll
        for (int k=0;k<8;k++) acc[k] = bp[k];
        #pragma unroll 4
        for (int i4=0;i4<32;i4++){
            const float x0 = X[(4*i4+0)*HW_ + hw];
            const float x1 = X[(4*i4+1)*HW_ + hw];
            const float x2 = X[(4*i4+2)*HW_ + hw];
            const float x3 = X[(4*i4+3)*HW_ + hw];
            #pragma unroll
            for (int k=0;k<8;k++){
                const float4 q = *(const float4*)&s_w0[(s*8+k)*128 + 4*i4];
                acc[k] += x0*q.x; acc[k] += x1*q.y; acc[k] += x2*q.z; acc[k] += x3*q.w;
            }
        }
        #pragma unroll
        for (int k=0;k<8;k++) s_A[w*33 + s*8 + k] = lrelu(acc[k]);
    }
    __syncthreads();

    // L1: 32 -> 32
    {
        float acc[8];
        const float* bp = b1_1 + h*32 + s*8;
        #pragma unroll
        for (int k=0;k<8;k++) acc[k] = bp[k];
        #pragma unroll
        for (int i4=0;i4<8;i4++){
            const float x0 = s_A[w*33 + 4*i4+0];
            const float x1 = s_A[w*33 + 4*i4+1];
            const float x2 = s_A[w*33 + 4*i4+2];
            const float x3 = s_A[w*33 + 4*i4+3];
            #pragma unroll
            for (int k=0;k<8;k++){
                const float4 q = *(const float4*)&s_w1[(s*8+k)*32 + 4*i4];
                acc[k] += x0*q.x; acc[k] += x1*q.y; acc[k] += x2*q.z; acc[k] += x3*q.w;
            }
        }
        #pragma unroll
        for (int k=0;k<8;k++) s_B[w*33 + s*8 + k] = lrelu(acc[k]);
    }
    __syncthreads();

    // L2: 32 -> 8 (each s owns 2 outputs; no activation)
    {
        float acc[2];
        const float* bp = b1_2 + h*8 + s*2;
        acc[0] = bp[0]; acc[1] = bp[1];
        #pragma unroll
        for (int i4=0;i4<8;i4++){
            const float x0 = s_B[w*33 + 4*i4+0];
            const float x1 = s_B[w*33 + 4*i4+1];
            const float x2 = s_B[w*33 + 4*i4+2];
            const float x3 = s_B[w*33 + 4*i4+3];
            #pragma unroll
            for (int k=0;k<2;k++){
                const float4 q = *(const float4*)&s_w2[(s*2+k)*32 + 4*i4];
                acc[k] += x0*q.x; acc[k] += x1*q.y; acc[k] += x2*q.z; acc[k] += x3*q.w;
            }
        }
        s_A[w*33 + s*2 + 0] = acc[0];
        s_A[w*33 + s*2 + 1] = acc[1];
    }
    __syncthreads();

    if (s == 0){
        const float* sc = &s_A[w*33];
        float best = sc[0]; int bi = 0;
        #pragma unroll
        for (int k=1;k<8;k++){ const float v = sc[k]; if (v > best){ best = v; bi = k; } }
        s_ind[w] = bi;
    }
    __syncthreads();

    int raw12 = 0;   // only meaningful in s==0 threads

    // ================= stage 2 =================
    {
        const int e = s_ind[w] + 8*h;
        // L0: 128 -> 32  (per-lane expert gather, float4)
        {
            float acc[8];
            const float4 b0 = *(const float4*)&b2_0[e*32 + s*8];
            const float4 b1 = *(const float4*)&b2_0[e*32 + s*8 + 4];
            acc[0]=b0.x; acc[1]=b0.y; acc[2]=b0.z; acc[3]=b0.w;
            acc[4]=b1.x; acc[5]=b1.y; acc[6]=b1.z; acc[7]=b1.w;
            const float* wp = w2_0 + (size_t)e*4096 + s*8;
            #pragma unroll 4
            for (int i=0;i<128;i++){
                const float xv = X[i*HW_ + hw];
                const float4 a = *(const float4*)&wp[i*32];
                const float4 b = *(const float4*)&wp[i*32 + 4];
                acc[0]+=xv*a.x; acc[1]+=xv*a.y; acc[2]+=xv*a.z; acc[3]+=xv*a.w;
                acc[4]+=xv*b.x; acc[5]+=xv*b.y; acc[6]+=xv*b.z; acc[7]+=xv*b.w;
            }
            #pragma unroll
            for (int k=0;k<8;k++) s_A[w*33 + s*8 + k] = lrelu(acc[k]);
        }
        __syncthreads();
        // L1: 32 -> 32
        {
            float acc[8];
            const float4 b0 = *(const float4*)&b2_1[e*32 + s*8];
            const float4 b1 = *(const float4*)&b2_1[e*32 + s*8 + 4];
            acc[0]=b0.x; acc[1]=b0.y; acc[2]=b0.z; acc[3]=b0.w;
            acc[4]=b1.x; acc[5]=b1.y; acc[6]=b1.z; acc[7]=b1.w;
            const float* wp = w2_1 + (size_t)e*1024 + s*8;
            #pragma unroll 4
            for (int i=0;i<32;i++){
                const float xv = s_A[w*33 + i];
                const float4 a = *(const float4*)&wp[i*32];
                const float4 b = *(const float4*)&wp[i*32 + 4];
                acc[0]+=xv*a.x; acc[1]+=xv*a.y; acc[2]+=xv*a.z; acc[3]+=xv*a.w;
                acc[4]+=xv*b.x; acc[5]+=xv*b.y; acc[6]+=xv*b.z; acc[7]+=xv*b.w;
            }
            #pragma unroll
            for (int k=0;k<8;k++) s_B[w*33 + s*8 + k] = lrelu(acc[k]);
        }
        __syncthreads();
        // L2: 32 -> 16 (each s owns 4 outputs; raw scores)
        {
            float acc[4];
            const float4 b0 = *(const float4*)&b2_2[e*16 + s*4];
            acc[0]=b0.x; acc[1]=b0.y; acc[2]=b0.z; acc[3]=b0.w;
            const float* wp = w2_2 + (size_t)e*512 + s*4;
            #pragma unroll 4
            for (int i=0;i<32;i++){
                const float xv = s_B[w*33 + i];
                const float4 a = *(const float4*)&wp[i*16];
                acc[0]+=xv*a.x; acc[1]+=xv*a.y; acc[2]+=xv*a.z; acc[3]+=xv*a.w;
            }
            #pragma unroll
            for (int k=0;k<4;k++) s_A[w*33 + s*4 + k] = acc[k];
        }
        __syncthreads();
        if (s == 0){
            const float* sc = &s_A[w*33];
            float best = sc[0]; int bi = 0;
            #pragma unroll
            for (int k=1;k<16;k++){ const float v = sc[k]; if (v > best){ best = v; bi = k; } }
            const int ind1 = s_ind[w];
            raw12 = ind1*8 + bi - 4;                 // unclipped inds12
            int cl = raw12 < 0 ? 0 : (raw12 > 63 ? 63 : raw12);
            s_ind[w] = cl;
        }
        __syncthreads();
    }

    // ================= stage 3 =================
    {
        const int e = s_ind[w] + 64*h;
        // L0: 128 -> 32
        {
            float acc[8];
            const float4 b0 = *(const float4*)&b3_0[e*32 + s*8];
            const float4 b1 = *(const float4*)&b3_0[e*32 + s*8 + 4];
            acc[0]=b0.x; acc[1]=b0.y; acc[2]=b0.z; acc[3]=b0.w;
            acc[4]=b1.x; acc[5]=b1.y; acc[6]=b1.z; acc[7]=b1.w;
            const float* wp = w3_0 + (size_t)e*4096 + s*8;
            #pragma unroll 4
            for (int i=0;i<128;i++){
                const float xv = X[i*HW_ + hw];
                const float4 a = *(const float4*)&wp[i*32];
                const float4 b = *(const float4*)&wp[i*32 + 4];
                acc[0]+=xv*a.x; acc[1]+=xv*a.y; acc[2]+=xv*a.z; acc[3]+=xv*a.w;
                acc[4]+=xv*b.x; acc[5]+=xv*b.y; acc[6]+=xv*b.z; acc[7]+=xv*b.w;
            }
            #pragma unroll
            for (int k=0;k<8;k++) s_A[w*33 + s*8 + k] = lrelu(acc[k]);
        }
        __syncthreads();
        // L1: 32 -> 32
        {
            float acc[8];
            const float4 b0 = *(const float4*)&b3_1[e*32 + s*8];
            const float4 b1 = *(const float4*)&b3_1[e*32 + s*8 + 4];
            acc[0]=b0.x; acc[1]=b0.y; acc[2]=b0.z; acc[3]=b0.w;
            acc[4]=b1.x; acc[5]=b1.y; acc[6]=b1.z; acc[7]=b1.w;
            const float* wp = w3_1 + (size_t)e*1024 + s*8;
            #pragma unroll 4
            for (int i=0;i<32;i++){
                const float xv = s_A[w*33 + i];
                const float4 a = *(const float4*)&wp[i*32];
                const float4 b = *(const float4*)&wp[i*32 + 4];
                acc[0]+=xv*a.x; acc[1]+=xv*a.y; acc[2]+=xv*a.z; acc[3]+=xv*a.w;
                acc[4]+=xv*b.x; acc[5]+=xv*b.y; acc[6]+=xv*b.z; acc[7]+=xv*b.w;
            }
            #pragma unroll
            for (int k=0;k<8;k++) s_B[w*33 + s*8 + k] = lrelu(acc[k]);
        }
        __syncthreads();
        // L2: 32 -> 16
        {
            float acc[4];
            const float4 b0 = *(const float4*)&b3_2[e*16 + s*4];
            acc[0]=b0.x; acc[1]=b0.y; acc[2]=b0.z; acc[3]=b0.w;
            const float* wp = w3_2 + (size_t)e*512 + s*4;
            #pragma unroll 4
            for (int i=0;i<32;i++){
                const float xv = s_B[w*33 + i];
                const float4 a = *(const float4*)&wp[i*16];
                acc[0]+=xv*a.x; acc[1]+=xv*a.y; acc[2]+=xv*a.z; acc[3]+=xv*a.w;
            }
            #pragma unroll
            for (int k=0;k<4;k++) s_A[w*33 + s*4 + k] = acc[k];
        }
        __syncthreads();
        if (s == 0){
            const float* sc = &s_A[w*33];
            float best = sc[0]; int bi = 0;
            #pragma unroll
            for (int k=1;k<16;k++){ const float v = sc[k]; if (v > best){ best = v; bi = k; } }
            int v = raw12*8 + bi - 4;
            v = v < 0 ? 0 : (v > 511 ? 511 : v);
            out[hw] = v;
        }
    }
}

extern "C" void kernel_launch(void* const* d_in, const int* in_sizes, int n_in,
                              void* d_out, int out_size, void* d_ws, size_t ws_size,
                              hipStream_t stream) {
    const float* X    = (const float*)d_in[0];
    const float* w1_0 = (const float*)d_in[1];
    const float* b1_0 = (const float*)d_in[2];
    const float* w1_1 = (const float*)d_in[3];
    const float* b1_1 = (const float*)d_in[4];
    const float* w1_2 = (const float*)d_in[5];
    const float* b1_2 = (const float*)d_in[6];
    const float* w2_0 = (const float*)d_in[7];
    const float* b2_0 = (const float*)d_in[8];
    const float* w2_1 = (const float*)d_in[9];
    const float* b2_1 = (const float*)d_in[10];
    const float* w2_2 = (const float*)d_in[11];
    const float* b2_2 = (const float*)d_in[12];
    const float* w3_0 = (const float*)d_in[13];
    const float* b3_0 = (const float*)d_in[14];
    const float* w3_1 = (const float*)d_in[15];
    const float* b3_1 = (const float*)d_in[16];
    const float* w3_2 = (const float*)d_in[17];
    const float* b3_2 = (const float*)d_in[18];
    int* out = (int*)d_out;

    cls3_fused<<<H_, 384, 0, stream>>>(X,
        w1_0, b1_0, w1_1, b1_1, w1_2, b1_2,
        w2_0, b2_0, w2_1, b2_1, w2_2, b2_2,
        w3_0, b3_0, w3_1, b3_1, w3_2, b3_2,
        out);
}